// Round 3
// baseline (101.320 us; speedup 1.0000x reference)
//
#include <hip/hip_runtime.h>
#include <math.h>

// Fused HybridEstimatorQNN forward:
//   q = sin(x0) * sin(x1 + w)
//   h1 = tanh([x0,x1,q] @ W1 + b1)   (3->8)
//   h2 = tanh(h1 @ W2 + b2)          (8->4)
//   out = h2 @ W3 + b3               (4->1)
//
// tanh(x) = 2r - 1, r = rcp(1 + exp2(-2*log2e*x)); the affine "2r-1" is
// folded into the next layer (W' = 2W, b' = b - sum(W)).
//
// 8 elements/thread: 4x float4 loads issued up-front (latency overlaps the
// per-thread param fold), 2x float4 stores. Amortizes the ~85-op param
// hoist over 8 elements instead of 4.

#define NEG2LOG2E -2.8853900817779268f
#define INV2PI     0.15915494309189535f

__device__ __forceinline__ float sigm2(float x) {
    // r = 1/(1 + e^{-2x}) = (tanh(x)+1)/2 ; saturates correctly at +-inf.
    float t = __builtin_amdgcn_exp2f(x * NEG2LOG2E);
    return __builtin_amdgcn_rcpf(1.0f + t);
}

__global__ __launch_bounds__(256) void qnn_fused_kernel(
    const float* __restrict__ in,   // [n,2]
    const float* __restrict__ W1,   // [3,8]
    const float* __restrict__ b1,   // [8]
    const float* __restrict__ W2,   // [8,4]
    const float* __restrict__ b2,   // [4]
    const float* __restrict__ W3,   // [4,1]
    const float* __restrict__ b3,   // [1]
    const float* __restrict__ wq,   // [1]
    float* __restrict__ out,        // [n]
    int n)
{
    const int base = (blockIdx.x * blockDim.x + threadIdx.x) * 8;

    // ---- fast path: issue all global loads first (MLP latency hiding) ----
    float4 p0, p1, p2, p3;
    const bool fast = (base + 7 < n);
    if (fast) {
        const float4* src = reinterpret_cast<const float4*>(in + 2 * base);
        p0 = src[0];
        p1 = src[1];
        p2 = src[2];
        p3 = src[3];
    }

    // ---- hoist + pre-fold params (uniform addresses -> scalar regs) ----
    const float wC = wq[0] * INV2PI;        // folded into sin argument

    float w1[3][8];
#pragma unroll
    for (int i = 0; i < 3; ++i)
#pragma unroll
        for (int j = 0; j < 8; ++j) w1[i][j] = W1[i * 8 + j];
    float bb1[8];
#pragma unroll
    for (int j = 0; j < 8; ++j) bb1[j] = b1[j];

    // layer 2 folded: acc = (b2_j - sum_i W2_ij) + sum_i r1_i * (2 W2_ij)
    float w2d[8][4];
    float bb2p[4];
#pragma unroll
    for (int j = 0; j < 4; ++j) {
        float s = 0.0f;
#pragma unroll
        for (int i = 0; i < 8; ++i) {
            float v = W2[i * 4 + j];
            w2d[i][j] = 2.0f * v;
            s += v;
        }
        bb2p[j] = b2[j] - s;
    }

    // layer 3 folded: out = (b3 - sum_i W3_i) + sum_i r2_i * (2 W3_i)
    float w3d[4];
    float s3 = 0.0f;
#pragma unroll
    for (int i = 0; i < 4; ++i) { float v = W3[i]; w3d[i] = 2.0f * v; s3 += v; }
    const float bb3p = b3[0] - s3;

    auto forward = [&](float x0, float x1) -> float {
        float q = __builtin_amdgcn_sinf(x0 * INV2PI)
                * __builtin_amdgcn_sinf(fmaf(x1, INV2PI, wC));
        float r1[8];
#pragma unroll
        for (int j = 0; j < 8; ++j) {
            float acc = fmaf(x0, w1[0][j],
                        fmaf(x1, w1[1][j],
                        fmaf(q,  w1[2][j], bb1[j])));
            r1[j] = sigm2(acc);
        }
        float r2[4];
#pragma unroll
        for (int j = 0; j < 4; ++j) {
            float acc = bb2p[j];
#pragma unroll
            for (int i = 0; i < 8; ++i) acc = fmaf(r1[i], w2d[i][j], acc);
            r2[j] = sigm2(acc);
        }
        float o = bb3p;
#pragma unroll
        for (int i = 0; i < 4; ++i) o = fmaf(r2[i], w3d[i], o);
        return o;
    };

    if (fast) {
        float4 o0, o1;
        o0.x = forward(p0.x, p0.y);
        o0.y = forward(p0.z, p0.w);
        o0.z = forward(p1.x, p1.y);
        o0.w = forward(p1.z, p1.w);
        o1.x = forward(p2.x, p2.y);
        o1.y = forward(p2.z, p2.w);
        o1.z = forward(p3.x, p3.y);
        o1.w = forward(p3.z, p3.w);
        float4* dst = reinterpret_cast<float4*>(out + base);
        dst[0] = o0;
        dst[1] = o1;
    } else {
        // tail
        for (int e = 0; e < 8; ++e) {
            int i = base + e;
            if (i < n) out[i] = forward(in[2 * i], in[2 * i + 1]);
        }
    }
}

extern "C" void kernel_launch(void* const* d_in, const int* in_sizes, int n_in,
                              void* d_out, int out_size, void* d_ws, size_t ws_size,
                              hipStream_t stream) {
    const float* in = (const float*)d_in[0];
    const float* W1 = (const float*)d_in[1];
    const float* b1 = (const float*)d_in[2];
    const float* W2 = (const float*)d_in[3];
    const float* b2 = (const float*)d_in[4];
    const float* W3 = (const float*)d_in[5];
    const float* b3 = (const float*)d_in[6];
    const float* wq = (const float*)d_in[7];
    float* out = (float*)d_out;

    const int n = out_size;                 // B rows
    const int threads = 256;
    const int elems_per_block = threads * 8;
    const int blocks = (n + elems_per_block - 1) / elems_per_block;

    hipLaunchKernelGGL(qnn_fused_kernel, dim3(blocks), dim3(threads), 0, stream,
                       in, W1, b1, W2, b2, W3, b3, wq, out, n);
}

// Round 5
// 97.815 us; speedup vs baseline: 1.0358x; 1.0358x over previous
//
#include <hip/hip_runtime.h>
#include <math.h>

// Fused HybridEstimatorQNN forward:
//   q = sin(x0) * sin(x1 + w)
//   h1 = tanh([x0,x1,q] @ W1 + b1)   (3->8)
//   h2 = tanh(h1 @ W2 + b2)          (8->4)
//   out = h2 @ W3 + b3               (4->1)
//
// tanh(x) = 2r - 1, r = rcp(1 + exp2(-2*log2e*x)); the affine "2r-1" is
// folded into the next layer (W' = 2W, b' = b - sum(W)).
//
// Issue-count optimizations (kernel is VALU+trans issue-bound):
//  - packed fp32 (v_pk_fma_f32 et al.) across the NEURON axis: weights are
//    stored as float2 pairs; per-element scalars (x0, x1, q, r1_i) are
//    splatted, which VOP3P op_sel encodes for free. Halves MLP FMA slots.
//  - paired reciprocal inside each sigm2 pair: rcp(a), rcp(b) ->
//    rd = rcp(a*b); {b*rd, a*rd}. Cuts 12 rcp/elem -> 6. Trans 26 -> 20.
//    Safe: exp2 overflow needs pre-act < -44; ours are bounded ~|20|.
//  - packed final dot: 2x pk_fma + 1 horizontal add instead of 4 fmaf.

#define NEG2LOG2E -2.8853900817779268f
#define INV2PI     0.15915494309189535f

typedef float v2f __attribute__((ext_vector_type(2)));

__device__ __forceinline__ v2f pk_fma(v2f a, v2f b, v2f c) {
    return __builtin_elementwise_fma(a, b, c);
}

// Paired r = 1/(1+exp2(c*x)) for two neurons at once.
__device__ __forceinline__ v2f sigm2_pair(v2f x) {
    v2f xm = x * NEG2LOG2E;                      // v_pk_mul_f32
    v2f t;
    t.x = __builtin_amdgcn_exp2f(xm.x);
    t.y = __builtin_amdgcn_exp2f(xm.y);
    v2f a = t + 1.0f;                            // v_pk_add_f32
    float rd = __builtin_amdgcn_rcpf(a.x * a.y); // one rcp for the pair
    v2f r;
    r.x = a.y * rd;
    r.y = a.x * rd;
    return r;
}

__global__ __launch_bounds__(256) void qnn_fused_kernel(
    const float* __restrict__ in,   // [n,2]
    const float* __restrict__ W1,   // [3,8]
    const float* __restrict__ b1,   // [8]
    const float* __restrict__ W2,   // [8,4]
    const float* __restrict__ b2,   // [4]
    const float* __restrict__ W3,   // [4,1]
    const float* __restrict__ b3,   // [1]
    const float* __restrict__ wq,   // [1]
    float* __restrict__ out,        // [n]
    int n)
{
    const int base = (blockIdx.x * blockDim.x + threadIdx.x) * 4;

    // ---- issue global loads first (latency overlaps the param fold) ----
    float4 p0, p1;
    const bool fast = (base + 3 < n);
    if (fast) {
        const float4* src = reinterpret_cast<const float4*>(in + 2 * base);
        p0 = src[0];
        p1 = src[1];
    }

    // ---- hoist + pre-fold params (uniform values, packed as pairs) ----
    const float wC = wq[0] * INV2PI;             // folded into sin argument

    v2f w1v[3][4];                               // [in][neuron-pair]
#pragma unroll
    for (int i = 0; i < 3; ++i)
#pragma unroll
        for (int jp = 0; jp < 4; ++jp) {
            w1v[i][jp].x = W1[i * 8 + 2 * jp];
            w1v[i][jp].y = W1[i * 8 + 2 * jp + 1];
        }
    v2f b1v[4];
#pragma unroll
    for (int jp = 0; jp < 4; ++jp) { b1v[jp].x = b1[2 * jp]; b1v[jp].y = b1[2 * jp + 1]; }

    // layer 2 folded: acc = (b2_j - sum_i W2_ij) + sum_i r1_i * (2 W2_ij)
    v2f w2v[8][2];                               // [in-neuron][out-pair], doubled
    v2f b2v[2];                                  // folded
#pragma unroll
    for (int jp = 0; jp < 2; ++jp) {
        float s0 = 0.0f, s1 = 0.0f;
#pragma unroll
        for (int i = 0; i < 8; ++i) {
            float vx = W2[i * 4 + 2 * jp];
            float vy = W2[i * 4 + 2 * jp + 1];
            w2v[i][jp].x = 2.0f * vx;
            w2v[i][jp].y = 2.0f * vy;
            s0 += vx; s1 += vy;
        }
        b2v[jp].x = b2[2 * jp] - s0;
        b2v[jp].y = b2[2 * jp + 1] - s1;
    }

    // layer 3 folded: out = (b3 - sum_i W3_i) + sum_i r2_i * (2 W3_i)
    v2f w3v[2];
    float s3 = 0.0f;
#pragma unroll
    for (int i = 0; i < 4; ++i) { float v = W3[i]; (i < 2 ? w3v[0] : w3v[1])[i & 1] = 2.0f * v; s3 += v; }
    const float bb3p = b3[0] - s3;

    auto forward = [&](float x0, float x1) -> float {
        float q = __builtin_amdgcn_sinf(x0 * INV2PI)
                * __builtin_amdgcn_sinf(fmaf(x1, INV2PI, wC));
        v2f x0v = {x0, x0}, x1v = {x1, x1}, qv = {q, q};

        v2f r1[4];
#pragma unroll
        for (int jp = 0; jp < 4; ++jp) {
            v2f acc = pk_fma(x0v, w1v[0][jp],
                      pk_fma(x1v, w1v[1][jp],
                      pk_fma(qv,  w1v[2][jp], b1v[jp])));
            r1[jp] = sigm2_pair(acc);
        }

        v2f r2[2];
#pragma unroll
        for (int jp = 0; jp < 2; ++jp) {
            v2f acc = b2v[jp];
#pragma unroll
            for (int ip = 0; ip < 4; ++ip) {
                v2f rlo = {r1[ip].x, r1[ip].x};   // op_sel-encodable splats
                v2f rhi = {r1[ip].y, r1[ip].y};
                acc = pk_fma(rlo, w2v[2 * ip][jp], acc);
                acc = pk_fma(rhi, w2v[2 * ip + 1][jp], acc);
            }
            r2[jp] = sigm2_pair(acc);
        }

        // packed final dot: {bb3p,0} + r2[0]*w3v[0] + r2[1]*w3v[1], then h-add
        v2f oacc = {bb3p, 0.0f};
        oacc = pk_fma(r2[0], w3v[0], oacc);
        oacc = pk_fma(r2[1], w3v[1], oacc);
        return oacc.x + oacc.y;
    };

    if (fast) {
        float4 o;
        o.x = forward(p0.x, p0.y);
        o.y = forward(p0.z, p0.w);
        o.z = forward(p1.x, p1.y);
        o.w = forward(p1.z, p1.w);
        *reinterpret_cast<float4*>(out + base) = o;
    } else {
        // tail
        for (int e = 0; e < 4; ++e) {
            int i = base + e;
            if (i < n) out[i] = forward(in[2 * i], in[2 * i + 1]);
        }
    }
}

extern "C" void kernel_launch(void* const* d_in, const int* in_sizes, int n_in,
                              void* d_out, int out_size, void* d_ws, size_t ws_size,
                              hipStream_t stream) {
    const float* in = (const float*)d_in[0];
    const float* W1 = (const float*)d_in[1];
    const float* b1 = (const float*)d_in[2];
    const float* W2 = (const float*)d_in[3];
    const float* b2 = (const float*)d_in[4];
    const float* W3 = (const float*)d_in[5];
    const float* b3 = (const float*)d_in[6];
    const float* wq = (const float*)d_in[7];
    float* out = (float*)d_out;

    const int n = out_size;                 // B rows
    const int threads = 256;
    const int elems_per_block = threads * 4;
    const int blocks = (n + elems_per_block - 1) / elems_per_block;

    hipLaunchKernelGGL(qnn_fused_kernel, dim3(blocks), dim3(threads), 0, stream,
                       in, W1, b1, W2, b2, W3, b3, wq, out, n);
}